// Round 24
// baseline (170.176 us; speedup 1.0000x reference)
//
#include <hip/hip_runtime.h>

#define TSTEPS 2048
#define BATCH  4096
#define HID    4
#define STRIDE (BATCH*HID)    // 16384 floats per timestep slab
#define CH     32             // timesteps per chunk (barrier period)
#define NCHUNK (TSTEPS/CH)    // 64 source chunks
#define NPH    69             // T3 finishes m=63 at p=66; 69 = 3*23

// Broadcast component k (0..3) to all 4 lanes of each quad via DPP quad_perm.
#define QB(v,k) __int_as_float(__builtin_amdgcn_update_dpp( \
    0, __float_as_int(v), (k)*0x55, 0xF, 0xF, true))

__device__ __forceinline__ float fast_exp2(float x) {
#if __has_builtin(__builtin_amdgcn_exp2f)
  return __builtin_amdgcn_exp2f(x);
#else
  return exp2f(x);
#endif
}
__device__ __forceinline__ float fast_rcp(float x) {
#if __has_builtin(__builtin_amdgcn_rcpf)
  return __builtin_amdgcn_rcpf(x);
#else
  return 1.0f / x;
#endif
}

// Direct global->LDS 4B load (wave-uniform LDS base + lane*4).
__device__ __forceinline__ void xload(float* ldst, const float* gsrc) {
  __builtin_amdgcn_global_load_lds(
      (const __attribute__((address_space(1))) void*)gsrc,
      (__attribute__((address_space(3))) void*)ldst, 4, 0, 0);
}

// Dual-group chain-paired pipeline (r23 structure x2 groups per block).
// 128 blocks x 5 waves: w0=P_A, w4=P_B (producers; share SIMD0 under
// round-robin w%4 placement - both latency-tolerant), w1..w3 = T1..T3 solo.
// Each T-wave runs the recurrence for TWO independent 64-unit groups (A,B):
// the chains' trans latencies pipeline (r11 evidence), B's issue fills A's
// stalls -> C_pair < 2x C_single.
//   P_g : x staging (3-slot gll ring, vmcnt(32)) + ai0 -> aif[0][g]
//   T1  : chains L0 (A,B) + DPP-shared ai1 (paired b64) -> aif[1][g]
//   T2  : chains L1 (A,B) + DPP-shared ai2 -> aif[2][g]
//   T3  : chains L2 (A,B) + Y stores
// Math (r22/r23-verified): recurrence on r = 1/(1+exp2(a)), h = 1-2r folded:
//   chain: a = av[u] + whp.quad(r), whp = -2K*Whh[l]
//   ai consumes the SAME quad(r): wip = -2K*Wih[l+1],
//   cbn = K*(b[l+1] + Whh[l+1].1 + Wih[l+1].1); P: wip=K*Wih0, no Wih sum.
// Protocol (r23-verified per group): double-buffered ifaces (par=m&1, write
// at m+l, read m+l+1, next same-parity write m+l+2 -> race-free), ONE raw
// s_barrier per phase, lgkmcnt(0) drained before it, vmcnt counted (32) on
// P waves only, never drained in-loop.
__global__ __launch_bounds__(320) void rnn_dualp(
    const float* __restrict__ X,    // (T, B, H)
    const float* __restrict__ H0,   // (L, B, H)
    const float* __restrict__ Wih,  // (L, H, H)
    const float* __restrict__ Whh,  // (L, H, H)
    const float* __restrict__ bih,  // (L, H)
    const float* __restrict__ bhh,  // (L, H)
    float* __restrict__ Y)          // (T, B, H)
{
  const int lane = threadIdx.x & 63;
  const int w    = threadIdx.x >> 6;            // 0..4
  const bool isP = (w == 0) || (w == 4);
  const int  pg  = (w == 4) ? 1 : 0;            // producer's group
  const int  gA  = blockIdx.x * 128 + lane;     // group A unit
  const int  gB  = gA + 64;                     // group B unit
  const int  gP  = pg ? gB : gA;                // producer's unit
  const int  j   = lane & 3;
  const float K  = 2.8853900817779268f;         // 2*log2(e)

  __shared__ float xbuf[2][3][CH][64];          // 48 KB [grp][slot][u][lane]
  __shared__ float aif[3][2][2][CH/2][64][2];   // 96 KB [l][grp][par][pr][ln][2]

  // Weights.
  float whp[HID], wip[HID], cbn = 0.0f, rA = 0.0f, rB = 0.0f;
  if (isP) {                                    // ai0 from raw x
    float wsum = 0.0f;
#pragma unroll
    for (int k = 0; k < HID; ++k) {
      wip[k] = K * Wih[(0*HID + j)*HID + k];
      wsum  += Whh[(0*HID + j)*HID + k];
    }
    cbn = K * (bih[0*HID + j] + bhh[0*HID + j] + wsum);
  } else {
    const int Lt = w - 1;                       // chain layer
#pragma unroll
    for (int k = 0; k < HID; ++k)
      whp[k] = -2.0f * K * Whh[(Lt*HID + j)*HID + k];
    rA = 0.5f * (1.0f - H0[Lt*STRIDE + gA]);    // h = 1 - 2r
    rB = 0.5f * (1.0f - H0[Lt*STRIDE + gB]);
    if (w <= 2) {                               // ai(l+1) from quad(r), folded
      const int Ln = w;
      float wsum = 0.0f;
#pragma unroll
      for (int k = 0; k < HID; ++k) {
        float wik = Wih[(Ln*HID + j)*HID + k];
        wip[k] = -2.0f * K * wik;
        wsum  += Whh[(Ln*HID + j)*HID + k] + wik;
      }
      cbn = K * (bih[Ln*HID + j] + bhh[Ln*HID + j] + wsum);
    }
  }

  const float* __restrict__ xp = X + gP;

  // Prime the x pipeline (each P wave: 64 outstanding, per-wave vmcnt).
  if (isP) {
    __builtin_amdgcn_sched_barrier(0);
    asm volatile("s_waitcnt vmcnt(0)" ::: "memory");
#pragma unroll
    for (int u = 0; u < CH; ++u)
      xload(&xbuf[pg][0][u][0], xp + (size_t)(0*CH + u) * STRIDE);
#pragma unroll
    for (int u = 0; u < CH; ++u)
      xload(&xbuf[pg][1][u][0], xp + (size_t)(1*CH + u) * STRIDE);
  }

  auto phase = [&](int p, int slot) {
    if (isP) {
      if (p <= NCHUNK - 1) {
        const int par = p & 1;
        asm volatile("s_waitcnt vmcnt(32)" ::: "memory");
        __builtin_amdgcn_sched_barrier(0);
        float xv[CH];
#pragma unroll
        for (int u = 0; u < CH; ++u) xv[u] = xbuf[pg][slot][u][lane];
        __builtin_amdgcn_sched_barrier(0);
        float apend = 0.0f;
#pragma unroll
        for (int u = 0; u < CH; ++u) {
          float a = cbn;
          a = fmaf(QB(xv[u], 0), wip[0], a);
          a = fmaf(QB(xv[u], 1), wip[1], a);
          a = fmaf(QB(xv[u], 2), wip[2], a);
          a = fmaf(QB(xv[u], 3), wip[3], a);
          if (u & 1) {
            float2 pr = {apend, a};
            *(float2*)&aif[0][pg][par][u >> 1][lane][0] = pr;
          } else {
            apend = a;
          }
        }
#pragma unroll
        for (int u = 0; u < CH; ++u) {
          int tn = (p + 2) * CH + u;
          if (tn > TSTEPS - 1) tn = TSTEPS - 1; // clamped tail: never read
          xload(&xbuf[pg][(slot+2)%3][u][0], xp + (size_t)tn * STRIDE);
        }
      }
    } else {
      const int m = p - w;                      // T_w: chunk m = p - w
      if (m >= 0 && m <= NCHUNK - 1) {
        const int par = m & 1;
        float avA[CH], avB[CH];
#pragma unroll
        for (int q = 0; q < CH/2; ++q) {
          float2 vA = *(const float2*)&aif[w-1][0][par][q][lane][0];
          avA[2*q] = vA.x; avA[2*q+1] = vA.y;
          float2 vB = *(const float2*)&aif[w-1][1][par][q][lane][0];
          avB[2*q] = vB.x; avB[2*q+1] = vB.y;
        }
        __builtin_amdgcn_sched_barrier(0);
        if (w <= 2) {
          // dual chains + DPP-shared delayed ai, b64-paired writes
          float apA = 0.0f, apB = 0.0f;
#pragma unroll
          for (int u = 0; u < CH; ++u) {
            float a0 = QB(rA, 0), a1 = QB(rA, 1), a2 = QB(rA, 2), a3 = QB(rA, 3);
            float b0 = QB(rB, 0), b1 = QB(rB, 1), b2 = QB(rB, 2), b3 = QB(rB, 3);
            if (u > 0) {
              float aa = cbn;
              aa = fmaf(a0, wip[0], aa);
              aa = fmaf(a1, wip[1], aa);
              aa = fmaf(a2, wip[2], aa);
              aa = fmaf(a3, wip[3], aa);
              float ab = cbn;
              ab = fmaf(b0, wip[0], ab);
              ab = fmaf(b1, wip[1], ab);
              ab = fmaf(b2, wip[2], ab);
              ab = fmaf(b3, wip[3], ab);
              if (u & 1) {
                apA = aa; apB = ab;
              } else {
                float2 prA = {apA, aa};
                *(float2*)&aif[w][0][par][(u-2) >> 1][lane][0] = prA;
                float2 prB = {apB, ab};
                *(float2*)&aif[w][1][par][(u-2) >> 1][lane][0] = prB;
              }
            }
            float tA0 = fmaf(a0, whp[0], avA[u]);
            float tA1 = a1 * whp[1];
            tA0 = fmaf(a2, whp[2], tA0);
            tA1 = fmaf(a3, whp[3], tA1);
            rA = fast_rcp(fast_exp2(tA0 + tA1) + 1.0f);
            float tB0 = fmaf(b0, whp[0], avB[u]);
            float tB1 = b1 * whp[1];
            tB0 = fmaf(b2, whp[2], tB0);
            tB1 = fmaf(b3, whp[3], tB1);
            rB = fast_rcp(fast_exp2(tB0 + tB1) + 1.0f);
          }
          {                                     // epilogue: {ai(30), ai(31)}
            float a0 = QB(rA, 0), a1 = QB(rA, 1), a2 = QB(rA, 2), a3 = QB(rA, 3);
            float b0 = QB(rB, 0), b1 = QB(rB, 1), b2 = QB(rB, 2), b3 = QB(rB, 3);
            float aa = cbn;
            aa = fmaf(a0, wip[0], aa);
            aa = fmaf(a1, wip[1], aa);
            aa = fmaf(a2, wip[2], aa);
            aa = fmaf(a3, wip[3], aa);
            float ab = cbn;
            ab = fmaf(b0, wip[0], ab);
            ab = fmaf(b1, wip[1], ab);
            ab = fmaf(b2, wip[2], ab);
            ab = fmaf(b3, wip[3], ab);
            float2 prA = {apA, aa};
            *(float2*)&aif[w][0][par][(CH-2) >> 1][lane][0] = prA;
            float2 prB = {apB, ab};
            *(float2*)&aif[w][1][par][(CH-2) >> 1][lane][0] = prB;
          }
        } else {
          const int base = m * CH;              // final layer: chains + Y
#pragma unroll
          for (int u = 0; u < CH; ++u) {
            float tA0 = fmaf(QB(rA, 0), whp[0], avA[u]);
            float tA1 =      QB(rA, 1) * whp[1];
            tA0 = fmaf(QB(rA, 2), whp[2], tA0);
            tA1 = fmaf(QB(rA, 3), whp[3], tA1);
            rA = fast_rcp(fast_exp2(tA0 + tA1) + 1.0f);
            float tB0 = fmaf(QB(rB, 0), whp[0], avB[u]);
            float tB1 =      QB(rB, 1) * whp[1];
            tB0 = fmaf(QB(rB, 2), whp[2], tB0);
            tB1 = fmaf(QB(rB, 3), whp[3], tB1);
            rB = fast_rcp(fast_exp2(tB0 + tB1) + 1.0f);
            Y[(size_t)(base + u) * STRIDE + gA] = fmaf(-2.0f, rA, 1.0f);
            Y[(size_t)(base + u) * STRIDE + gB] = fmaf(-2.0f, rB, 1.0f);
          }
        }
      }
    }

    // phase boundary: drain LDS ops only (NOT vmcnt), then raw barrier.
    __builtin_amdgcn_sched_barrier(0);
    asm volatile("s_waitcnt lgkmcnt(0)" ::: "memory");
    __builtin_amdgcn_s_barrier();
    __builtin_amdgcn_sched_barrier(0);
  };

  for (int p = 0; p < NPH; p += 3) {   // 69 = 3 * 23, static xbuf slots
    phase(p + 0, 0);
    phase(p + 1, 1);
    phase(p + 2, 2);
  }

  // drain outstanding (clamped-tail) staging loads before LDS dealloc
  if (isP) asm volatile("s_waitcnt vmcnt(0)" ::: "memory");
}

extern "C" void kernel_launch(void* const* d_in, const int* in_sizes, int n_in,
                              void* d_out, int out_size, void* d_ws, size_t ws_size,
                              hipStream_t stream) {
  const float* X   = (const float*)d_in[0];
  const float* H0  = (const float*)d_in[1];
  const float* Wih = (const float*)d_in[2];
  const float* Whh = (const float*)d_in[3];
  const float* bih = (const float*)d_in[4];
  const float* bhh = (const float*)d_in[5];
  float* Y = (float*)d_out;

  // 128 blocks x 320 threads: P_A + P_B (shared SIMD) + 3 dual-chain T waves.
  rnn_dualp<<<dim3(STRIDE / 128), dim3(320), 0, stream>>>(X, H0, Wih, Whh, bih, bhh, Y);
}

// Round 25
// 102.599 us; speedup vs baseline: 1.6587x; 1.6587x over previous
//
#include <hip/hip_runtime.h>

#define TSTEPS 2048
#define BATCH  4096
#define HID    4
#define STRIDE (BATCH*HID)    // 16384 floats per timestep slab
#define CH     32             // timesteps per chunk (barrier period)
#define NCHUNK (TSTEPS/CH)    // 64 source chunks
#define NPH    69             // >= NCHUNK+4, = 3*23 for static slot rotation

// Broadcast component k (0..3) to all 4 lanes of each quad via DPP quad_perm.
#define QB(v,k) __int_as_float(__builtin_amdgcn_update_dpp( \
    0, __float_as_int(v), (k)*0x55, 0xF, 0xF, true))

__device__ __forceinline__ float fast_exp2(float x) {
#if __has_builtin(__builtin_amdgcn_exp2f)
  return __builtin_amdgcn_exp2f(x);
#else
  return exp2f(x);
#endif
}
__device__ __forceinline__ float fast_rcp(float x) {
#if __has_builtin(__builtin_amdgcn_rcpf)
  return __builtin_amdgcn_rcpf(x);
#else
  return 1.0f / x;
#endif
}

// Direct global->LDS 4B load (wave-uniform LDS base + lane*4).
__device__ __forceinline__ void xload(float* ldst, const float* gsrc) {
  __builtin_amdgcn_global_load_lds(
      (const __attribute__((address_space(1))) void*)gsrc,
      (__attribute__((address_space(3))) void*)ldst, 4, 0, 0);
}

// r23 BEST (102.7us): r15 topology + DPP-sharing issue-diet + b64-paired
// iface handoffs. Measured decomposition: chain 69 cyc/step (r14 probe) +
// machinery 37.5 (r20 probe) + ai-residual ~5 = 111.7 cyc/step = 102.7us.
// Within 5% of the measured compositional floor; all structural
// alternatives (r16/r17/r18/r21/r24) and activation substitutions (r12/r13)
// regressed or failed. Serial-dependence-latency-bound.
//   wave 0 (P) : x staging + ai0 (paired writes) -> iface[0]
//   wave 1 (T1): chain L0 + DPP-shared ai1 (paired) -> iface[1]
//   wave 2 (T2): chain L1 + DPP-shared ai2 (paired) -> iface[2]
//   wave 3 (T3): chain L2 + Y store (scalar global)
// Recurrence on r = 1/(1+exp2(a)), h = 1-2r folded into ALL weights:
//   chain: a = av[u] + whp.quad(r),  whp = -2K*Whh[l]
//   ai consumes the SAME quad(r): wip = -2K*Wih[l+1],
//   cbn = K*(b[l+1] + Whh[l+1].1 + Wih[l+1].1).
// Protocol: double-buffered ifaces (par = m&1), ONE raw s_barrier per phase,
// lgkmcnt(0) drained before it, vmcnt counted (32), never drained in-loop.
__global__ __launch_bounds__(256) void rnn_pipe4(
    const float* __restrict__ X,    // (T, B, H)
    const float* __restrict__ H0,   // (L, B, H)
    const float* __restrict__ Wih,  // (L, H, H)
    const float* __restrict__ Whh,  // (L, H, H)
    const float* __restrict__ bih,  // (L, H)
    const float* __restrict__ bhh,  // (L, H)
    float* __restrict__ Y)          // (T, B, H)
{
  const int lane = threadIdx.x & 63;
  const int wid  = threadIdx.x >> 6;           // 0 = producer; 1..3 = layers
  const int g    = blockIdx.x * 64 + lane;     // global (b,j) unit
  const int j    = g & 3;
  const float K  = 2.8853900817779268f;        // 2*log2(e)

  __shared__ float iface[3][2][CH/2][64][2];   // 48 KB, b64-paired handoff
  __shared__ float xbuf[3][CH][64];            // 24 KB: x staging ring

  float whp[HID], wip[HID], cbn = 0.0f, r = 0.0f;
  {
    const int Lt = wid - 1;                    // tail layer
    const int Ln = wid;                        // next-ai layer
    if (wid >= 1) {
#pragma unroll
      for (int k = 0; k < HID; ++k)
        whp[k] = -2.0f * K * Whh[(Lt*HID + j)*HID + k];
      r = 0.5f * (1.0f - H0[Lt*STRIDE + g]);   // h = 1 - 2r
    }
    if (wid == 0) {                            // ai0 from raw x
      float wsum = 0.0f;
#pragma unroll
      for (int k = 0; k < HID; ++k) {
        wip[k] = K * Wih[(Ln*HID + j)*HID + k];
        wsum  += Whh[(Ln*HID + j)*HID + k];
      }
      cbn = K * (bih[Ln*HID + j] + bhh[Ln*HID + j] + wsum);
    } else if (wid <= 2) {                     // ai(l+1) from quad(r), folded
      float wsum = 0.0f;
#pragma unroll
      for (int k = 0; k < HID; ++k) {
        float wik = Wih[(Ln*HID + j)*HID + k];
        wip[k] = -2.0f * K * wik;
        wsum  += Whh[(Ln*HID + j)*HID + k] + wik;
      }
      cbn = K * (bih[Ln*HID + j] + bhh[Ln*HID + j] + wsum);
    }
  }

  const float* __restrict__ xp = X + g;

  if (wid == 0) {
    __builtin_amdgcn_sched_barrier(0);
    asm volatile("s_waitcnt vmcnt(0)" ::: "memory");
#pragma unroll
    for (int u = 0; u < CH; ++u)
      xload(&xbuf[0][u][0], xp + (size_t)(0*CH + u) * STRIDE);
#pragma unroll
    for (int u = 0; u < CH; ++u)
      xload(&xbuf[1][u][0], xp + (size_t)(1*CH + u) * STRIDE);
  }

  auto phase = [&](int p, int slot) {
    if (wid == 0) {
      if (p <= NCHUNK - 1) {
        const int par = p & 1;
        asm volatile("s_waitcnt vmcnt(32)" ::: "memory");
        __builtin_amdgcn_sched_barrier(0);
        float xv[CH];
#pragma unroll
        for (int u = 0; u < CH; ++u) xv[u] = xbuf[slot][u][lane];
        __builtin_amdgcn_sched_barrier(0);
        float apend = 0.0f;
#pragma unroll
        for (int u = 0; u < CH; ++u) {
          float a = cbn;
          a = fmaf(QB(xv[u], 0), wip[0], a);
          a = fmaf(QB(xv[u], 1), wip[1], a);
          a = fmaf(QB(xv[u], 2), wip[2], a);
          a = fmaf(QB(xv[u], 3), wip[3], a);
          if (u & 1) {
            float2 pr = {apend, a};
            *(float2*)&iface[0][par][u >> 1][lane][0] = pr;
          } else {
            apend = a;
          }
        }
#pragma unroll
        for (int u = 0; u < CH; ++u) {
          int tn = (p + 2) * CH + u;
          if (tn > TSTEPS - 1) tn = TSTEPS - 1;
          xload(&xbuf[(slot+2)%3][u][0], xp + (size_t)tn * STRIDE);
        }
      }
    } else {
      const int m = p - wid;
      if (m >= 0 && m <= NCHUNK - 1) {
        const int par = m & 1;
        float av[CH];
#pragma unroll
        for (int p2 = 0; p2 < CH/2; ++p2) {
          float2 v = *(const float2*)&iface[wid-1][par][p2][lane][0];
          av[2*p2]   = v.x;
          av[2*p2+1] = v.y;
        }
        __builtin_amdgcn_sched_barrier(0);
        if (wid <= 2) {
          // chain + DPP-shared ai, b64-paired writes (ai(u-1) at step u;
          // pairs {ai(u-2),ai(u-1)} written at even u; epilogue last pair)
          float apend = 0.0f;
#pragma unroll
          for (int u = 0; u < CH; ++u) {
            float d0 = QB(r, 0), d1 = QB(r, 1), d2 = QB(r, 2), d3 = QB(r, 3);
            if (u > 0) {
              float a = cbn;
              a = fmaf(d0, wip[0], a);
              a = fmaf(d1, wip[1], a);
              a = fmaf(d2, wip[2], a);
              a = fmaf(d3, wip[3], a);
              if (u & 1) {                      // u odd: ai(u-1) even -> hold
                apend = a;
              } else {                          // u even: write {ai(u-2),ai(u-1)}
                float2 pr = {apend, a};
                *(float2*)&iface[wid][par][(u-2) >> 1][lane][0] = pr;
              }
            }
            float t0 = fmaf(d0, whp[0], av[u]);
            float t1 = d1 * whp[1];
            t0 = fmaf(d2, whp[2], t0);
            t1 = fmaf(d3, whp[3], t1);
            r = fast_rcp(fast_exp2(t0 + t1) + 1.0f);
          }
          {                                     // epilogue: {ai(30), ai(31)}
            float d0 = QB(r, 0), d1 = QB(r, 1), d2 = QB(r, 2), d3 = QB(r, 3);
            float a = cbn;
            a = fmaf(d0, wip[0], a);
            a = fmaf(d1, wip[1], a);
            a = fmaf(d2, wip[2], a);
            a = fmaf(d3, wip[3], a);
            float2 pr = {apend, a};
            *(float2*)&iface[wid][par][(CH-2) >> 1][lane][0] = pr;
          }
        } else {
          const int base = m * CH;              // final layer: chain + Y
#pragma unroll
          for (int u = 0; u < CH; ++u) {
            float t0 = fmaf(QB(r, 0), whp[0], av[u]);
            float t1 =      QB(r, 1) * whp[1];
            t0 = fmaf(QB(r, 2), whp[2], t0);
            t1 = fmaf(QB(r, 3), whp[3], t1);
            r = fast_rcp(fast_exp2(t0 + t1) + 1.0f);
            Y[(size_t)(base + u) * STRIDE + g] = fmaf(-2.0f, r, 1.0f);
          }
        }
      }
    }

    __builtin_amdgcn_sched_barrier(0);
    asm volatile("s_waitcnt lgkmcnt(0)" ::: "memory");
    __builtin_amdgcn_s_barrier();
    __builtin_amdgcn_sched_barrier(0);
  };

  for (int p = 0; p < NPH; p += 3) {
    phase(p + 0, 0);
    phase(p + 1, 1);
    phase(p + 2, 2);
  }

  if (wid == 0) asm volatile("s_waitcnt vmcnt(0)" ::: "memory");
}

extern "C" void kernel_launch(void* const* d_in, const int* in_sizes, int n_in,
                              void* d_out, int out_size, void* d_ws, size_t ws_size,
                              hipStream_t stream) {
  const float* X   = (const float*)d_in[0];
  const float* H0  = (const float*)d_in[1];
  const float* Wih = (const float*)d_in[2];
  const float* Whh = (const float*)d_in[3];
  const float* bih = (const float*)d_in[4];
  const float* bhh = (const float*)d_in[5];
  float* Y = (float*)d_out;

  // 256 blocks x 256 threads: producer + 3 layer waves per CU.
  rnn_pipe4<<<dim3(STRIDE / 64), dim3(256), 0, stream>>>(X, H0, Wih, Whh, bih, bhh, Y);
}